// Round 6
// baseline (333.815 us; speedup 1.0000x reference)
//
#include <hip/hip_runtime.h>

typedef __attribute__((ext_vector_type(8))) short short8;
typedef __attribute__((ext_vector_type(4))) float f32x4;

#define XP_ELEMS (32u * 66u * 66u * 128u)  /* 17,842,176 bf16 elements */
#define WT_ELEMS (256u * 1152u)            /* 294,912 bf16 elements */
#define WS_NEED  ((size_t)(XP_ELEMS + WT_ELEMS) * 2u)

typedef const __attribute__((address_space(1))) void* gp1_t;
typedef __attribute__((address_space(3))) void* lp3_t;
typedef const __attribute__((address_space(1))) short8* g8p_t;

__device__ __forceinline__ void gload16(const void* g, void* l) {
  __builtin_amdgcn_global_load_lds((gp1_t)g, (lp3_t)l, 16, 0, 0);
}

__device__ __forceinline__ short f2bf(float f) {
  unsigned u = __float_as_uint(f);
  u = (u + 0x7FFFu + ((u >> 16) & 1u)) >> 16;  // RNE truncate to bf16
  return (short)u;
}

// Transpose one (b, y) plane: x[b][cin][y][px] fp32 -> x_p[b][y+1][px+1][cin] bf16.
__global__ __launch_bounds__(256) void prepass_x(const float* __restrict__ x,
                                                 short* __restrict__ xp) {
  __shared__ short lds[64 * 128];  // [px][cin, granule-swizzled], 16 KB
  const int y = blockIdx.x;   // 0..63
  const int b = blockIdx.y;   // 0..31
  const int t = threadIdx.x;

  const float* src = x + (long)b * 128 * 4096 + y * 64;
#pragma unroll
  for (int i = 0; i < 8; ++i) {
    int f4 = t + i * 256;          // 0..2047
    int cin = f4 >> 4, px4 = f4 & 15;
    float4 v = *(const float4*)(src + (long)cin * 4096 + px4 * 4);
    float vv[4] = {v.x, v.y, v.z, v.w};
#pragma unroll
    for (int j = 0; j < 4; ++j) {
      int px = px4 * 4 + j;
      int g = (cin >> 3) ^ ((px ^ (px >> 2)) & 15);
      lds[px * 128 + (g << 3) + (cin & 7)] = f2bf(vv[j]);
    }
  }
  __syncthreads();
  short* dst = xp + ((long)(b * 66 + y + 1) * 66 + 1) * 128;
#pragma unroll
  for (int i = 0; i < 4; ++i) {
    int f8 = t + i * 256;          // 0..1023
    int px = f8 >> 4, c8 = f8 & 15;
    int g = c8 ^ ((px ^ (px >> 2)) & 15);
    short8 v = *(const short8*)&lds[px * 128 + (g << 3)];
    *(short8*)(dst + (long)px * 128 + c8 * 8) = v;
  }
  short8 z = (short8)0;
  short* rowbase = xp + (long)(b * 66 + y + 1) * 66 * 128;
  if (t < 32) {
    int px = (t < 16) ? 0 : 65;
    int c8 = t & 15;
    *(short8*)(rowbase + (long)px * 128 + c8 * 8) = z;
  }
  if (y == 0) {
    short* r0 = xp + (long)(b * 66) * 66 * 128;
    for (int idx = t; idx < 66 * 16; idx += 256) *(short8*)(r0 + idx * 8) = z;
  }
  if (y == 63) {
    short* r65 = xp + ((long)(b * 66) + 65) * 66 * 128;
    for (int idx = t; idx < 66 * 16; idx += 256) *(short8*)(r65 + idx * 8) = z;
  }
}

// weight[cout][cin][kh][kw] fp32 -> w_t[cout][kh][kw][cin] bf16
__global__ __launch_bounds__(256) void prepass_w(const float* __restrict__ w,
                                                 short* __restrict__ wt) {
  int o    = blockIdx.x * 256 + threadIdx.x;  // < 294912 exactly
  int cout = o / 1152;
  int r    = o % 1152;
  int kh   = r / 384;
  int kw   = (r / 128) % 3;
  int cin  = r & 127;
  wt[o] = f2bf(w[((cout * 128 + cin) * 3 + kh) * 3 + kw]);
}

// Implicit-GEMM conv, register-pipelined:
//   Tile 128x128, 4 waves (2x2, 64x64/wave, acc[4][4]), BK=32.
//   KEY CHANGES vs rounds 0-5 (which all serialized LDS-service and MFMA
//   inside each chunk and pinned at 27-34% MfmaUtil):
//   (1) cur/nxt register double-buffer: iter ks issues A-ds_reads + B-loads
//       for ks+1, waits for LAST iter's loads with counted lgkmcnt(4)/
//       vmcnt(6), and MFMAs on registers resident for a full iteration.
//   (2) B operand bypasses LDS entirely: lane-exact 16B rows of xp loaded
//       global->reg (xp is L2/L3-resident; FETCH=30MB proved it).  LDS
//       holds A only: ring-4 x 8KB = 32 KB/CTA -> 3 CTAs/CU.
//   vm ledger (6 vm ops/iter: 2 stage + 4 B): steady invariant entering
//   iter ks = {S(ks+2)[2], B(ks)[4]} outstanding; VMC(6) certifies B(ks)
//   (and pre-certifies S(ks+2), so ARD(ks+2) next iter needs no wait);
//   LGKM(4) certifies ARD(ks) (4 newest = this iter's ARD(ks+1)).
//   Counts are fence-segment based: intra-segment reorder can't break them.
//   One barrier/iter (A-slot WAR: ARD(ks-1) lgkm-waited before bar(ks-1),
//   which precedes S(ks+3)'s overwrite at iter ks).
__global__ __launch_bounds__(256, 3) void conv_gemm(const short* __restrict__ xp,
                                                    const short* __restrict__ wt,
                                                    float* __restrict__ out) {
  __shared__ alignas(16) short Alds[4 * 128 * 32];  // ring-4, 32 KB
  const int tid   = threadIdx.x;
  const int w     = tid >> 6;   // wave id 0..3
  const int l     = tid & 63;
  const int l15   = l & 15;
  const int q     = l >> 4;
  const int ntile = blockIdx.x;       // 0..1023 (n-tiles of 128)
  const int m0    = blockIdx.y << 7;  // 0 or 128

  // ---- A staging decomposition: thread -> (row r, granule p)
  const int r  = tid >> 2;            // 0..63
  const int p  = tid & 3;
  const int cs = p ^ ((r >> 1) & 3);  // source k-granule (swizzle, self-inverse)
  const long aoff0 = (long)(m0 + r) * 1152 + (cs << 3);
  const long aoff1 = aoff0 + (long)64 * 1152;
  const int ldst0 = r * 32 + p * 8;   // LDS short-offset, rows 0..63
  const int ldst1 = ldst0 + 2048;     // rows 64..127

  // ---- A frag read offsets within a slot (conflict-free, verified r0/r5)
  const int wm = (w >> 1) << 6;  // wave's 64-row offset in tile (M)
  const int wn = (w & 1) << 6;   // wave's 64-col offset in tile (N)
  int aRd[4];
#pragma unroll
  for (int i = 0; i < 4; ++i) {
    int rA = wm + (i << 4) + l15;
    aRd[i] = rA * 32 + ((q ^ ((rA >> 1) & 3)) << 3);
  }

  // ---- B per-lane base: row nb = ntile*128 + wn + l15 (j*16 never crosses y)
  const int nb  = (ntile << 7) + wn + l15;
  const int bbi = nb >> 12, byy = (nb >> 6) & 63, bxx = nb & 63;
  const short* bbase = xp + ((long)(bbi * 66 + byy) * 66 + bxx) * 128 + (q << 3);

  f32x4 acc[4][4];
#pragma unroll
  for (int i = 0; i < 4; ++i)
#pragma unroll
    for (int j = 0; j < 4; ++j) acc[i][j] = (f32x4)0.f;

  short8 aF0[4], aF1[4], bF0[4], bF1[4];

#define BAR()   __builtin_amdgcn_s_barrier()
#define SBAR()  __builtin_amdgcn_sched_barrier(0)
#define LGK(n)  asm volatile("s_waitcnt lgkmcnt(" #n ")" ::: "memory")
#define VMC(n)  asm volatile("s_waitcnt vmcnt(" #n ")" ::: "memory")

  // stage A chunk ks into slot ks&3 (2 gload_lds)
  auto STG = [&](int ks) {
    const int sb = (ks & 3) << 12;
    gload16(wt + aoff0 + ((long)ks << 5), &Alds[sb + ldst0]);
    gload16(wt + aoff1 + ((long)ks << 5), &Alds[sb + ldst1]);
  };
  // B chunk ks -> frag regs (4 global_load_dwordx4, addrspace(1))
  auto LDB = [&](int ks, short8 (&bN)[4]) {
    const int kq = ks >> 2;
    const int kh = kq / 3, kw2 = kq - kh * 3;
    const short* bp = bbase + ((kh * 66 + kw2) << 7) + ((ks & 3) << 5);
#pragma unroll
    for (int j = 0; j < 4; ++j)
      bN[j] = *(g8p_t)(bp + j * 2048);
  };
  // A chunk ks frag ds_reads (4 x ds_read_b128)
  auto ARD = [&](int ks, short8 (&aN)[4]) {
    const int sb = (ks & 3) << 12;
#pragma unroll
    for (int i = 0; i < 4; ++i)
      aN[i] = *(const short8*)&Alds[sb + aRd[i]];
  };
  auto MM = [&](short8 (&aC)[4], short8 (&bC)[4]) {
    __builtin_amdgcn_s_setprio(1);
#pragma unroll
    for (int i = 0; i < 4; ++i)
#pragma unroll
      for (int j = 0; j < 4; ++j)
        acc[i][j] = __builtin_amdgcn_mfma_f32_16x16x32_bf16(aC[i], bC[j],
                                                            acc[i][j], 0, 0, 0);
    __builtin_amdgcn_s_setprio(0);
  };

  // steady-iter body: process chunk ks on (aC,bC); prefetch ks+1 into (aN,bN)
  auto BODY = [&](int ks, short8 (&aC)[4], short8 (&aN)[4],
                          short8 (&bC)[4], short8 (&bN)[4]) {
    STG(ks + 3);          // 2 vm
    LDB(ks + 1, bN);      // 4 vm
    ARD(ks + 1, aN);      // 4 ds (slot ks+1 certified last iter)
    LGK(4);               // ARD(ks) done
    VMC(6);               // B(ks) done (+ S(ks+2) pre-certified)
    SBAR();
    MM(aC, bC);
    BAR(); SBAR();
  };

  // ---- prologue: S(0),S(1),S(2),B(0); certify S(0),S(1); ARD(0)
  STG(0); STG(1); STG(2);   // 6 vm
  LDB(0, bF0);              // +4 = 10
  VMC(6);                   // certify S(0),S(1); leaves {S(2),B(0)} = invariant
  BAR(); SBAR();
  ARD(0, aF0);
  LGK(0);
  SBAR();

  // ---- steady: ks = 0..32 (stages S(3)..S(35)); parity: even ks -> cur buf0
#pragma unroll 1
  for (int it = 0; it < 16; ++it) {
    const int ks = it << 1;
    BODY(ks,     aF0, aF1, bF0, bF1);
    BODY(ks + 1, aF1, aF0, bF1, bF0);
  }
  BODY(32, aF0, aF1, bF0, bF1);

  // ---- tails (entering: outstanding {S(35),B(33)} = 6; S(34) certified)
  // i=33 (cur = buf1)
  LDB(34, bF0);             // out 10
  ARD(34, aF0);             // S(34) certified at i=32's VMC(6)
  LGK(4);                   // ARD(33) done
  VMC(4);                   // B(33) done (+S(35) certified); leaves B(34)
  SBAR();
  MM(aF1, bF1);
  BAR(); SBAR();
  // i=34 (cur = buf0)
  LDB(35, bF1);             // out 8
  ARD(35, aF1);             // S(35) certified above
  LGK(4);                   // ARD(34) done
  VMC(4);                   // B(34) done; leaves B(35)
  SBAR();
  MM(aF0, bF0);
  BAR(); SBAR();
  // i=35 (cur = buf1)
  LGK(0);
  VMC(0);
  SBAR();
  MM(aF1, bF1);

  // ---- epilogue: C/D layout col=lane&15, row=quad*4+reg (verified r0/r5)
  const int ngb = (ntile << 7) + wn;
  const int b   = ngb >> 12;
  const int yxb = ngb & 4095;
  float* outb = out + (long)b * (256 * 4096) + yxb + l15;
#pragma unroll
  for (int i = 0; i < 4; ++i) {
#pragma unroll
    for (int rr = 0; rr < 4; ++rr) {
      const int cout = m0 + wm + (i << 4) + q * 4 + rr;
      float* orow = outb + (long)cout * 4096;
#pragma unroll
      for (int j = 0; j < 4; ++j) orow[j * 16] = acc[i][j][rr];
    }
  }
#undef BAR
#undef SBAR
#undef LGK
#undef VMC
}

// Correctness fallback if workspace is too small (slow, fp32 direct conv).
__global__ __launch_bounds__(256) void naive_conv(const float* __restrict__ x,
                                                  const float* __restrict__ wgt,
                                                  float* __restrict__ out) {
  long o = (long)blockIdx.x * 256 + threadIdx.x;
  int xx = (int)(o & 63);
  int y  = (int)((o >> 6) & 63);
  int co = (int)((o >> 12) & 255);
  int b  = (int)(o >> 20);
  float s = 0.f;
  for (int ci = 0; ci < 128; ++ci) {
    for (int kh = 0; kh < 3; ++kh) {
      int iy = y + kh - 1;
      if (iy < 0 || iy > 63) continue;
      for (int kw = 0; kw < 3; ++kw) {
        int ix = xx + kw - 1;
        if (ix < 0 || ix > 63) continue;
        s += x[((long)(b * 128 + ci) * 64 + iy) * 64 + ix] *
             wgt[((co * 128 + ci) * 3 + kh) * 3 + kw];
      }
    }
  }
  out[o] = s;
}

extern "C" void kernel_launch(void* const* d_in, const int* in_sizes, int n_in,
                              void* d_out, int out_size, void* d_ws, size_t ws_size,
                              hipStream_t stream) {
  (void)in_sizes; (void)n_in;
  const float* x   = (const float*)d_in[0];
  const float* wgt = (const float*)d_in[1];
  float* out = (float*)d_out;
  if (ws_size >= WS_NEED) {
    short* xp = (short*)d_ws;
    short* wt = xp + XP_ELEMS;
    prepass_x<<<dim3(64, 32), dim3(256), 0, stream>>>(x, xp);
    prepass_w<<<dim3(WT_ELEMS / 256), dim3(256), 0, stream>>>(wgt, wt);
    conv_gemm<<<dim3(1024, 2), dim3(256), 0, stream>>>(xp, wt, out);
  } else {
    naive_conv<<<dim3(out_size / 256), dim3(256), 0, stream>>>(x, wgt, out);
  }
}

// Round 7
// 254.769 us; speedup vs baseline: 1.3103x; 1.3103x over previous
//
#include <hip/hip_runtime.h>

typedef __attribute__((ext_vector_type(8))) short short8;
typedef __attribute__((ext_vector_type(4))) float f32x4;

#define XP_ELEMS (32u * 66u * 66u * 128u)  /* 17,842,176 bf16 elements */
#define WT_ELEMS (256u * 1152u)            /* 294,912 bf16 elements */
#define WS_NEED  ((size_t)(XP_ELEMS + WT_ELEMS) * 2u)

typedef const __attribute__((address_space(1))) void* gp1_t;
typedef __attribute__((address_space(3))) void* lp3_t;

__device__ __forceinline__ void gload16(const void* g, void* l) {
  __builtin_amdgcn_global_load_lds((gp1_t)g, (lp3_t)l, 16, 0, 0);
}

__device__ __forceinline__ short f2bf(float f) {
  unsigned u = __float_as_uint(f);
  u = (u + 0x7FFFu + ((u >> 16) & 1u)) >> 16;  // RNE truncate to bf16
  return (short)u;
}

// Transpose one (b, y) plane: x[b][cin][y][px] fp32 -> x_p[b][y+1][px+1][cin] bf16.
__global__ __launch_bounds__(256) void prepass_x(const float* __restrict__ x,
                                                 short* __restrict__ xp) {
  __shared__ short lds[64 * 128];  // [px][cin, granule-swizzled], 16 KB
  const int y = blockIdx.x;   // 0..63
  const int b = blockIdx.y;   // 0..31
  const int t = threadIdx.x;

  const float* src = x + (long)b * 128 * 4096 + y * 64;
#pragma unroll
  for (int i = 0; i < 8; ++i) {
    int f4 = t + i * 256;          // 0..2047
    int cin = f4 >> 4, px4 = f4 & 15;
    float4 v = *(const float4*)(src + (long)cin * 4096 + px4 * 4);
    float vv[4] = {v.x, v.y, v.z, v.w};
#pragma unroll
    for (int j = 0; j < 4; ++j) {
      int px = px4 * 4 + j;
      int g = (cin >> 3) ^ ((px ^ (px >> 2)) & 15);
      lds[px * 128 + (g << 3) + (cin & 7)] = f2bf(vv[j]);
    }
  }
  __syncthreads();
  short* dst = xp + ((long)(b * 66 + y + 1) * 66 + 1) * 128;
#pragma unroll
  for (int i = 0; i < 4; ++i) {
    int f8 = t + i * 256;          // 0..1023
    int px = f8 >> 4, c8 = f8 & 15;
    int g = c8 ^ ((px ^ (px >> 2)) & 15);
    short8 v = *(const short8*)&lds[px * 128 + (g << 3)];
    *(short8*)(dst + (long)px * 128 + c8 * 8) = v;
  }
  short8 z = (short8)0;
  short* rowbase = xp + (long)(b * 66 + y + 1) * 66 * 128;
  if (t < 32) {
    int px = (t < 16) ? 0 : 65;
    int c8 = t & 15;
    *(short8*)(rowbase + (long)px * 128 + c8 * 8) = z;
  }
  if (y == 0) {
    short* r0 = xp + (long)(b * 66) * 66 * 128;
    for (int idx = t; idx < 66 * 16; idx += 256) *(short8*)(r0 + idx * 8) = z;
  }
  if (y == 63) {
    short* r65 = xp + ((long)(b * 66) + 65) * 66 * 128;
    for (int idx = t; idx < 66 * 16; idx += 256) *(short8*)(r65 + idx * 8) = z;
  }
}

// weight[cout][cin][kh][kw] fp32 -> w_t[cout][kh][kw][cin] bf16
__global__ __launch_bounds__(256) void prepass_w(const float* __restrict__ w,
                                                 short* __restrict__ wt) {
  int o    = blockIdx.x * 256 + threadIdx.x;  // < 294912 exactly
  int cout = o / 1152;
  int r    = o % 1152;
  int kh   = r / 384;
  int kw   = (r / 128) % 3;
  int cin  = r & 127;
  wt[o] = f2bf(w[((cout * 128 + cin) * 3 + kh) * 3 + kw]);
}

// Implicit-GEMM conv, m201-style 8-phase schedule.  Base = round-2 kernel
// (verified correct, 89.5 us).  SINGLE CHANGE vs round 2: all
// __builtin_amdgcn_sched_barrier(0) pins REMOVED (m141 evidence: order-
// pinning defeats the compiler's fine-grained lgkmcnt interleave and MFMA
// motion, -42% on the m97 GEMM).  The fence ledger is unchanged: counted
// vmcnt(4), lgkmcnt(8/0), raw s_barrier -- all with "memory" clobbers,
// which order MEMORY ops (ds_read/gload_lds can't cross) while leaving
// register-only MFMA/VALU free for the scheduler.  BAR() carries a
// zero-instruction compiler memory fence so post-barrier ds_reads cannot
// hoist above the barrier (cross-wave staging visibility).
__global__ __launch_bounds__(512, 2) void conv_gemm(const short* __restrict__ xp,
                                                    const short* __restrict__ wt,
                                                    float* __restrict__ out) {
  __shared__ alignas(16) short Alds[2 * 2 * 2 * 128 * 32];  // 64 KB
  __shared__ alignas(16) short Blds[2 * 2 * 2 * 128 * 32];  // 64 KB
  const int tid = threadIdx.x;
  const int w   = tid >> 6;     // wave 0..7
  const int l   = tid & 63;
  const int l15 = l & 15;
  const int q   = l >> 4;
  const int wm2 = w >> 2;       // wave M half 0..1
  const int wn4 = w & 3;        // wave N quarter 0..3
  const int ntile = blockIdx.x; // 0..511

  // ---- staging thread decomposition: t -> (chunk cc, row r6, granule pp)
  const int r6 = (tid >> 2) & 63;
  const int cc = tid >> 8;
  const int pp = tid & 3;
  const int cs = pp ^ ((r6 >> 1) & 3);              // source k-granule (swizzle)
  const int aTh  = r6 * 1152 + cc * 32 + cs * 8;    // A per-thread src offset
  const int ldsA = cc * 4096 + r6 * 32 + pp * 8;    // per-thread LDS dest
  const int ldsB0 = ldsA + ((r6 & 32) << 5);        // B unit n0: rows {0-31,64-95}
  int bTh[2][2];                                    // [hb][nq] per-thread B src
#pragma unroll
  for (int hb = 0; hb < 2; ++hb)
#pragma unroll
    for (int nq = 0; nq < 2; ++nq) {
      int R  = (r6 & 31) + ((r6 >> 5) << 6) + nq * 32;  // LDS row within half
      int n  = (ntile << 8) + (hb << 7) + R;
      int bb = n >> 12, yy = (n >> 6) & 63, xx = n & 63;
      bTh[hb][nq] = ((bb * 66 + yy) * 66 + xx) * 128 + cc * 32 + cs * 8;
    }

  // ---- frag read offsets (chunk-invariant, conflict-free)
  int aRd[8], bRd[4];
#pragma unroll
  for (int mi = 0; mi < 8; ++mi) {
    int r = (mi << 4) + l15;
    aRd[mi] = r * 32 + ((q ^ ((r >> 1) & 3)) << 3);
  }
#pragma unroll
  for (int nj = 0; nj < 4; ++nj) {
    int r = ((wn4 & 1) << 6) + (nj << 4) + l15;
    bRd[nj] = r * 32 + ((q ^ ((r >> 1) & 3)) << 3);
  }
  const int aHB = wm2 * 8192;        // wave's A half base (within slot)
  const int bHB = (wn4 >> 1) * 8192; // wave's B half base

  f32x4 acc[8][4];
#pragma unroll
  for (int mi = 0; mi < 8; ++mi)
#pragma unroll
    for (int nj = 0; nj < 4; ++nj) acc[mi][nj] = (f32x4)0.f;

  short8 af[4][2], bf[4][2];

  // ---- staging units: 2 gload_lds each (both h), 8 KB/unit
  auto ST_A = [&](int s, int v, int kb) {
    gload16(wt + kb + v * 73728 + aTh,
            &Alds[s * 16384 + v * 2048 + ldsA]);
    gload16(wt + kb + 147456 + v * 73728 + aTh,
            &Alds[s * 16384 + 8192 + v * 2048 + ldsA]);
  };
  auto ST_B = [&](int s, int nq, int sh) {
    gload16(xp + sh + bTh[0][nq], &Blds[s * 16384 + (nq << 10) + ldsB0]);
    gload16(xp + sh + bTh[1][nq], &Blds[s * 16384 + 8192 + (nq << 10) + ldsB0]);
  };
  auto LD_A = [&](int s, int mq) {
#pragma unroll
    for (int i = 0; i < 4; ++i)
#pragma unroll
      for (int c = 0; c < 2; ++c)
        af[i][c] = *(const short8*)&Alds[s * 16384 + aHB + c * 4096 + aRd[mq * 4 + i]];
  };
  auto LD_B = [&](int s, int nq) {
#pragma unroll
    for (int j = 0; j < 2; ++j)
#pragma unroll
      for (int c = 0; c < 2; ++c)
        bf[nq * 2 + j][c] =
            *(const short8*)&Blds[s * 16384 + bHB + c * 4096 + bRd[nq * 2 + j]];
  };
  auto MM = [&](int mq, int nq) {
    __builtin_amdgcn_s_setprio(1);
#pragma unroll
    for (int c = 0; c < 2; ++c)
#pragma unroll
      for (int i = 0; i < 4; ++i)
#pragma unroll
        for (int j = 0; j < 2; ++j)
          acc[mq * 4 + i][nq * 2 + j] = __builtin_amdgcn_mfma_f32_16x16x32_bf16(
              af[i][c], bf[nq * 2 + j][c], acc[mq * 4 + i][nq * 2 + j], 0, 0, 0);
    __builtin_amdgcn_s_setprio(0);
  };

#define BAR()   do { __builtin_amdgcn_s_barrier(); \
                     asm volatile("" ::: "memory"); } while (0)
#define LGKM0() asm volatile("s_waitcnt lgkmcnt(0)" ::: "memory")
#define LGKM8() asm volatile("s_waitcnt lgkmcnt(8)" ::: "memory")
#define VMC(n)  asm volatile("s_waitcnt vmcnt(" #n ")" ::: "memory")

  // ---- prologue: T0 (slot0) all 4 units + T1 (slot1) Av0, Bn0
  ST_A(0, 0, 0);  ST_B(0, 0, 0);     // T0.Av0, T0.Bn0   (khkw=0, cin-half 0)
  ST_A(0, 1, 0);  ST_B(0, 1, 0);     // T0.Av1, T0.Bn1
  ST_A(1, 0, 64); ST_B(1, 0, 64);    // T1.Av0, T1.Bn0   (cin-half 1)
  VMC(4);  // certify T0 (8 loads); T1's 4 remain in flight
  BAR();

#pragma unroll
  for (int J = 0; J < 9; ++J) {
    const int kh  = J / 3,        kw  = J % 3;
    const int khn = (J + 1) / 3,  kwn = (J + 1) % 3;
    const int kb1 = J * 128 + 64;           // A kbase, tile 2J+1
    const int kb2 = (J + 1) * 128;          // A kbase, tiles 2J+2 / 2J+3 (+64)
    const int sh1 = (kh * 66 + kw) * 128 + 64;    // B shift, tile 2J+1
    const int sh2 = (khn * 66 + kwn) * 128;       // B shift, tile 2J+2
    const int sh3 = sh2 + 64;                     // B shift, tile 2J+3

    // P0: T0 quad(0,0); stage slot1.Av1 (tile 2J+1)
    LD_A(0, 0); LD_B(0, 0);
    ST_A(1, 1, kb1);
    LGKM8();
    BAR(); LGKM0(); MM(0, 0); BAR();

    // P1: T0 quad(0,1); stage slot1.Bn1 (tile 2J+1)
    LD_B(0, 1);
    ST_B(1, 1, sh1);
    BAR(); LGKM0(); MM(0, 1); BAR();

    // P2: T0 quad(1,0); stage slot0.Av0 (tile 2J+2)
    LD_A(0, 1);
    if (J < 8) ST_A(0, 0, kb2);
    BAR(); LGKM0(); MM(1, 0); BAR();

    // P3: T0 quad(1,1); stage slot0.Bn0; fence certifies tile 2J+1
    if (J < 8) ST_B(0, 0, sh2);
    BAR(); LGKM0(); MM(1, 1);
    if (J < 8) { VMC(4); } else { VMC(0); }
    BAR();

    // P4: T1 quad(0,0); stage slot0.Av1 (tile 2J+2)
    LD_A(1, 0); LD_B(1, 0);
    if (J < 8) ST_A(0, 1, kb2);
    LGKM8();
    BAR(); LGKM0(); MM(0, 0); BAR();

    // P5: T1 quad(0,1); stage slot0.Bn1 (tile 2J+2)
    LD_B(1, 1);
    if (J < 8) ST_B(0, 1, sh2);
    BAR(); LGKM0(); MM(0, 1); BAR();

    // P6: T1 quad(1,0); stage slot1.Av0 (tile 2J+3)
    LD_A(1, 1);
    if (J < 8) ST_A(1, 0, kb2 + 64);
    BAR(); LGKM0(); MM(1, 0); BAR();

    // P7: T1 quad(1,1); stage slot1.Bn0 (tile 2J+3); fence certifies tile 2J+2
    if (J < 8) ST_B(1, 0, sh3);
    BAR(); LGKM0(); MM(1, 1);
    if (J < 8) { VMC(4); BAR(); }
  }

  // epilogue: C/D layout col=lane&15, row=quad*4+reg (m89/m91-verified)
  const int bimg = ntile >> 4;
  const int yx0  = ((ntile & 15) << 8) + (wn4 << 6) + l15;
  float* outb = out + (long)bimg * (256 * 4096) + yx0;
#pragma unroll
  for (int mi = 0; mi < 8; ++mi) {
#pragma unroll
    for (int r = 0; r < 4; ++r) {
      const int cout = (wm2 << 7) + (mi << 4) + (q << 2) + r;
      float* orow = outb + (long)cout * 4096;
#pragma unroll
      for (int nj = 0; nj < 4; ++nj) orow[nj << 4] = acc[mi][nj][r];
    }
  }
#undef BAR
#undef LGKM0
#undef LGKM8
#undef VMC
}

// Correctness fallback if workspace is too small (slow, fp32 direct conv).
__global__ __launch_bounds__(256) void naive_conv(const float* __restrict__ x,
                                                  const float* __restrict__ wgt,
                                                  float* __restrict__ out) {
  long o = (long)blockIdx.x * 256 + threadIdx.x;
  int xx = (int)(o & 63);
  int y  = (int)((o >> 6) & 63);
  int co = (int)((o >> 12) & 255);
  int b  = (int)(o >> 20);
  float s = 0.f;
  for (int ci = 0; ci < 128; ++ci) {
    for (int kh = 0; kh < 3; ++kh) {
      int iy = y + kh - 1;
      if (iy < 0 || iy > 63) continue;
      for (int kw = 0; kw < 3; ++kw) {
        int ix = xx + kw - 1;
        if (ix < 0 || ix > 63) continue;
        s += x[((long)(b * 128 + ci) * 64 + iy) * 64 + ix] *
             wgt[((co * 128 + ci) * 3 + kh) * 3 + kw];
      }
    }
  }
  out[o] = s;
}

extern "C" void kernel_launch(void* const* d_in, const int* in_sizes, int n_in,
                              void* d_out, int out_size, void* d_ws, size_t ws_size,
                              hipStream_t stream) {
  (void)in_sizes; (void)n_in;
  const float* x   = (const float*)d_in[0];
  const float* wgt = (const float*)d_in[1];
  float* out = (float*)d_out;
  if (ws_size >= WS_NEED) {
    short* xp = (short*)d_ws;
    short* wt = xp + XP_ELEMS;
    prepass_x<<<dim3(64, 32), dim3(256), 0, stream>>>(x, xp);
    prepass_w<<<dim3(WT_ELEMS / 256), dim3(256), 0, stream>>>(wgt, wt);
    conv_gemm<<<dim3(512), dim3(512), 0, stream>>>(xp, wt, out);
  } else {
    naive_conv<<<dim3(out_size / 256), dim3(256), 0, stream>>>(x, wgt, out);
  }
}

// Round 8
// 254.206 us; speedup vs baseline: 1.3132x; 1.0022x over previous
//
#include <hip/hip_runtime.h>

typedef __attribute__((ext_vector_type(8))) short short8;
typedef __attribute__((ext_vector_type(4))) float f32x4;

#define XP_ELEMS (32u * 66u * 66u * 128u)  /* 17,842,176 bf16 elements */
#define WT_ELEMS (256u * 1152u)            /* 294,912 bf16 elements */
#define WS_NEED  ((size_t)(XP_ELEMS + WT_ELEMS) * 2u)

typedef const __attribute__((address_space(1))) void* gp1_t;
typedef __attribute__((address_space(3))) void* lp3_t;

__device__ __forceinline__ void gload16(const void* g, void* l) {
  __builtin_amdgcn_global_load_lds((gp1_t)g, (lp3_t)l, 16, 0, 0);
}

__device__ __forceinline__ short f2bf(float f) {
  unsigned u = __float_as_uint(f);
  u = (u + 0x7FFFu + ((u >> 16) & 1u)) >> 16;  // RNE truncate to bf16
  return (short)u;
}

// Transpose one (b, y) plane: x[b][cin][y][px] fp32 -> x_p[b][y+1][px+1][cin] bf16.
__global__ __launch_bounds__(256) void prepass_x(const float* __restrict__ x,
                                                 short* __restrict__ xp) {
  __shared__ short lds[64 * 128];  // [px][cin, granule-swizzled], 16 KB
  const int y = blockIdx.x;   // 0..63
  const int b = blockIdx.y;   // 0..31
  const int t = threadIdx.x;

  const float* src = x + (long)b * 128 * 4096 + y * 64;
#pragma unroll
  for (int i = 0; i < 8; ++i) {
    int f4 = t + i * 256;          // 0..2047
    int cin = f4 >> 4, px4 = f4 & 15;
    float4 v = *(const float4*)(src + (long)cin * 4096 + px4 * 4);
    float vv[4] = {v.x, v.y, v.z, v.w};
#pragma unroll
    for (int j = 0; j < 4; ++j) {
      int px = px4 * 4 + j;
      int g = (cin >> 3) ^ ((px ^ (px >> 2)) & 15);
      lds[px * 128 + (g << 3) + (cin & 7)] = f2bf(vv[j]);
    }
  }
  __syncthreads();
  short* dst = xp + ((long)(b * 66 + y + 1) * 66 + 1) * 128;
#pragma unroll
  for (int i = 0; i < 4; ++i) {
    int f8 = t + i * 256;          // 0..1023
    int px = f8 >> 4, c8 = f8 & 15;
    int g = c8 ^ ((px ^ (px >> 2)) & 15);
    short8 v = *(const short8*)&lds[px * 128 + (g << 3)];
    *(short8*)(dst + (long)px * 128 + c8 * 8) = v;
  }
  short8 z = (short8)0;
  short* rowbase = xp + (long)(b * 66 + y + 1) * 66 * 128;
  if (t < 32) {
    int px = (t < 16) ? 0 : 65;
    int c8 = t & 15;
    *(short8*)(rowbase + (long)px * 128 + c8 * 8) = z;
  }
  if (y == 0) {
    short* r0 = xp + (long)(b * 66) * 66 * 128;
    for (int idx = t; idx < 66 * 16; idx += 256) *(short8*)(r0 + idx * 8) = z;
  }
  if (y == 63) {
    short* r65 = xp + ((long)(b * 66) + 65) * 66 * 128;
    for (int idx = t; idx < 66 * 16; idx += 256) *(short8*)(r65 + idx * 8) = z;
  }
}

// weight[cout][cin][kh][kw] fp32 -> w_t[cout][kh][kw][cin] bf16
__global__ __launch_bounds__(256) void prepass_w(const float* __restrict__ w,
                                                 short* __restrict__ wt) {
  int o    = blockIdx.x * 256 + threadIdx.x;  // < 294912 exactly
  int cout = o / 1152;
  int r    = o % 1152;
  int kh   = r / 384;
  int kw   = (r / 128) % 3;
  int cin  = r & 127;
  wt[o] = f2bf(w[((cout * 128 + cin) * 3 + kh) * 3 + kw]);
}

// Implicit-GEMM conv, 8-phase schedule with MINIMAL BARRIERS.
// Base = round-2/7 kernel (twice-verified ledger, 89.5 us, MfmaUtil 34%).
// SINGLE CHANGE vs round 7: barriers only at END of P1/P3/P5/P7 (4 per
// K-tile-pair) instead of 2 per phase (16).  Derivation (region ledger,
// slot regions Av0/Av1/Bn0/Bn1; "read" = frag ds_read, "ST" = overwrite):
//   slot0.Av0: read P0, ST P2  -> P1-end barrier covers
//   slot0.Bn0: read P0, ST P3  -> P1-end barrier covers
//   slot0.Av1: read P2, ST P4  -> P3-end barrier covers
//   slot0.Bn1: read P1, ST P5  -> P3-end barrier covers
//   slot1.*  : symmetric, covered by P5-end / P7-end (and prev-P7).
// RAW staging certification unchanged: VMC(4) + barrier at P3/P7 (per-wave
// FIFO ledger identical to R2).  Within each 2-phase barrier-free window,
// reads and STs touch DISJOINT regions (verified per window), and each
// wave waits only on its OWN lgkmcnt(0) before its MFMA -> waves skew, so
// one wave's MFMA cluster overlaps another wave's LDS service (m114
// mechanism).  This removes the block-wide lockstep that serialized the
// LDS burst (576-1150 cyc) with the MFMA burst (620 cyc) every phase.
__global__ __launch_bounds__(512, 2) void conv_gemm(const short* __restrict__ xp,
                                                    const short* __restrict__ wt,
                                                    float* __restrict__ out) {
  __shared__ alignas(16) short Alds[2 * 2 * 2 * 128 * 32];  // 64 KB
  __shared__ alignas(16) short Blds[2 * 2 * 2 * 128 * 32];  // 64 KB
  const int tid = threadIdx.x;
  const int w   = tid >> 6;     // wave 0..7
  const int l   = tid & 63;
  const int l15 = l & 15;
  const int q   = l >> 4;
  const int wm2 = w >> 2;       // wave M half 0..1
  const int wn4 = w & 3;        // wave N quarter 0..3
  const int ntile = blockIdx.x; // 0..511

  // ---- staging thread decomposition: t -> (chunk cc, row r6, granule pp)
  const int r6 = (tid >> 2) & 63;
  const int cc = tid >> 8;
  const int pp = tid & 3;
  const int cs = pp ^ ((r6 >> 1) & 3);              // source k-granule (swizzle)
  const int aTh  = r6 * 1152 + cc * 32 + cs * 8;    // A per-thread src offset
  const int ldsA = cc * 4096 + r6 * 32 + pp * 8;    // per-thread LDS dest
  const int ldsB0 = ldsA + ((r6 & 32) << 5);        // B unit n0: rows {0-31,64-95}
  int bTh[2][2];                                    // [hb][nq] per-thread B src
#pragma unroll
  for (int hb = 0; hb < 2; ++hb)
#pragma unroll
    for (int nq = 0; nq < 2; ++nq) {
      int R  = (r6 & 31) + ((r6 >> 5) << 6) + nq * 32;  // LDS row within half
      int n  = (ntile << 8) + (hb << 7) + R;
      int bb = n >> 12, yy = (n >> 6) & 63, xx = n & 63;
      bTh[hb][nq] = ((bb * 66 + yy) * 66 + xx) * 128 + cc * 32 + cs * 8;
    }

  // ---- frag read offsets (chunk-invariant, conflict-free)
  int aRd[8], bRd[4];
#pragma unroll
  for (int mi = 0; mi < 8; ++mi) {
    int r = (mi << 4) + l15;
    aRd[mi] = r * 32 + ((q ^ ((r >> 1) & 3)) << 3);
  }
#pragma unroll
  for (int nj = 0; nj < 4; ++nj) {
    int r = ((wn4 & 1) << 6) + (nj << 4) + l15;
    bRd[nj] = r * 32 + ((q ^ ((r >> 1) & 3)) << 3);
  }
  const int aHB = wm2 * 8192;        // wave's A half base (within slot)
  const int bHB = (wn4 >> 1) * 8192; // wave's B half base

  f32x4 acc[8][4];
#pragma unroll
  for (int mi = 0; mi < 8; ++mi)
#pragma unroll
    for (int nj = 0; nj < 4; ++nj) acc[mi][nj] = (f32x4)0.f;

  short8 af[4][2], bf[4][2];

  // ---- staging units: 2 gload_lds each (both h), 8 KB/unit
  auto ST_A = [&](int s, int v, int kb) {
    gload16(wt + kb + v * 73728 + aTh,
            &Alds[s * 16384 + v * 2048 + ldsA]);
    gload16(wt + kb + 147456 + v * 73728 + aTh,
            &Alds[s * 16384 + 8192 + v * 2048 + ldsA]);
  };
  auto ST_B = [&](int s, int nq, int sh) {
    gload16(xp + sh + bTh[0][nq], &Blds[s * 16384 + (nq << 10) + ldsB0]);
    gload16(xp + sh + bTh[1][nq], &Blds[s * 16384 + 8192 + (nq << 10) + ldsB0]);
  };
  auto LD_A = [&](int s, int mq) {
#pragma unroll
    for (int i = 0; i < 4; ++i)
#pragma unroll
      for (int c = 0; c < 2; ++c)
        af[i][c] = *(const short8*)&Alds[s * 16384 + aHB + c * 4096 + aRd[mq * 4 + i]];
  };
  auto LD_B = [&](int s, int nq) {
#pragma unroll
    for (int j = 0; j < 2; ++j)
#pragma unroll
      for (int c = 0; c < 2; ++c)
        bf[nq * 2 + j][c] =
            *(const short8*)&Blds[s * 16384 + bHB + c * 4096 + bRd[nq * 2 + j]];
  };
  auto MM = [&](int mq, int nq) {
    __builtin_amdgcn_s_setprio(1);
#pragma unroll
    for (int c = 0; c < 2; ++c)
#pragma unroll
      for (int i = 0; i < 4; ++i)
#pragma unroll
        for (int j = 0; j < 2; ++j)
          acc[mq * 4 + i][nq * 2 + j] = __builtin_amdgcn_mfma_f32_16x16x32_bf16(
              af[i][c], bf[nq * 2 + j][c], acc[mq * 4 + i][nq * 2 + j], 0, 0, 0);
    __builtin_amdgcn_s_setprio(0);
  };

#define BAR()   do { __builtin_amdgcn_s_barrier(); \
                     asm volatile("" ::: "memory"); } while (0)
#define LGKM0() asm volatile("s_waitcnt lgkmcnt(0)" ::: "memory")
#define VMC(n)  asm volatile("s_waitcnt vmcnt(" #n ")" ::: "memory")

  // ---- prologue: T0 (slot0) all 4 units + T1 (slot1) Av0, Bn0
  ST_A(0, 0, 0);  ST_B(0, 0, 0);     // T0.Av0, T0.Bn0   (khkw=0, cin-half 0)
  ST_A(0, 1, 0);  ST_B(0, 1, 0);     // T0.Av1, T0.Bn1
  ST_A(1, 0, 64); ST_B(1, 0, 64);    // T1.Av0, T1.Bn0   (cin-half 1)
  VMC(4);  // certify T0 (8 loads); T1's 4 remain in flight
  BAR();

#pragma unroll
  for (int J = 0; J < 9; ++J) {
    const int kh  = J / 3,        kw  = J % 3;
    const int khn = (J + 1) / 3,  kwn = (J + 1) % 3;
    const int kb1 = J * 128 + 64;           // A kbase, tile 2J+1
    const int kb2 = (J + 1) * 128;          // A kbase, tiles 2J+2 / 2J+3 (+64)
    const int sh1 = (kh * 66 + kw) * 128 + 64;    // B shift, tile 2J+1
    const int sh2 = (khn * 66 + kwn) * 128;       // B shift, tile 2J+2
    const int sh3 = sh2 + 64;                     // B shift, tile 2J+3

    // ---- window P0-P1 (barrier-free; reads slot0 v0/Bn0/Bn1, STs slot1 v1/Bn1)
    // P0
    LD_A(0, 0); LD_B(0, 0);
    ST_A(1, 1, kb1);
    LGKM0(); MM(0, 0);
    // P1
    LD_B(0, 1);
    ST_B(1, 1, sh1);
    LGKM0(); MM(0, 1);
    BAR();   // covers {slot0.Av0 readP0 -> ST P2, slot0.Bn0 readP0 -> ST P3}

    // ---- window P2-P3 (reads slot0 v1; STs slot0 v0/Bn0 -- disjoint)
    // P2
    LD_A(0, 1);
    if (J < 8) ST_A(0, 0, kb2);
    LGKM0(); MM(1, 0);
    // P3
    if (J < 8) ST_B(0, 0, sh2);
    LGKM0(); MM(1, 1);
    if (J < 8) { VMC(4); } else { VMC(0); }
    BAR();   // fence: tile 2J+1 certified block-wide

    // ---- window P4-P5 (reads slot1 v0/Bn0/Bn1; STs slot0 v1/Bn1 -- disjoint)
    // P4
    LD_A(1, 0); LD_B(1, 0);
    if (J < 8) ST_A(0, 1, kb2);
    LGKM0(); MM(0, 0);
    // P5
    LD_B(1, 1);
    if (J < 8) ST_B(0, 1, sh2);
    LGKM0(); MM(0, 1);
    BAR();   // covers {slot1.Av0 readP4 -> ST P6, slot1.Bn0 readP4 -> ST P7}

    // ---- window P6-P7 (reads slot1 v1; STs slot1 v0/Bn0 -- disjoint)
    // P6
    LD_A(1, 1);
    if (J < 8) ST_A(1, 0, kb2 + 64);
    LGKM0(); MM(1, 0);
    // P7
    if (J < 8) ST_B(1, 0, sh3);
    LGKM0(); MM(1, 1);
    if (J < 8) { VMC(4); BAR(); }   // fence: tile 2J+2 certified
  }

  // epilogue: C/D layout col=lane&15, row=quad*4+reg (m89/m91-verified)
  const int bimg = ntile >> 4;
  const int yx0  = ((ntile & 15) << 8) + (wn4 << 6) + l15;
  float* outb = out + (long)bimg * (256 * 4096) + yx0;
#pragma unroll
  for (int mi = 0; mi < 8; ++mi) {
#pragma unroll
    for (int r = 0; r < 4; ++r) {
      const int cout = (wm2 << 7) + (mi << 4) + (q << 2) + r;
      float* orow = outb + (long)cout * 4096;
#pragma unroll
      for (int nj = 0; nj < 4; ++nj) orow[nj << 4] = acc[mi][nj][r];
    }
  }
#undef BAR
#undef LGKM0
#undef VMC
}

// Correctness fallback if workspace is too small (slow, fp32 direct conv).
__global__ __launch_bounds__(256) void naive_conv(const float* __restrict__ x,
                                                  const float* __restrict__ wgt,
                                                  float* __restrict__ out) {
  long o = (long)blockIdx.x * 256 + threadIdx.x;
  int xx = (int)(o & 63);
  int y  = (int)((o >> 6) & 63);
  int co = (int)((o >> 12) & 255);
  int b  = (int)(o >> 20);
  float s = 0.f;
  for (int ci = 0; ci < 128; ++ci) {
    for (int kh = 0; kh < 3; ++kh) {
      int iy = y + kh - 1;
      if (iy < 0 || iy > 63) continue;
      for (int kw = 0; kw < 3; ++kw) {
        int ix = xx + kw - 1;
        if (ix < 0 || ix > 63) continue;
        s += x[((long)(b * 128 + ci) * 64 + iy) * 64 + ix] *
             wgt[((co * 128 + ci) * 3 + kh) * 3 + kw];
      }
    }
  }
  out[o] = s;
}

extern "C" void kernel_launch(void* const* d_in, const int* in_sizes, int n_in,
                              void* d_out, int out_size, void* d_ws, size_t ws_size,
                              hipStream_t stream) {
  (void)in_sizes; (void)n_in;
  const float* x   = (const float*)d_in[0];
  const float* wgt = (const float*)d_in[1];
  float* out = (float*)d_out;
  if (ws_size >= WS_NEED) {
    short* xp = (short*)d_ws;
    short* wt = xp + XP_ELEMS;
    prepass_x<<<dim3(64, 32), dim3(256), 0, stream>>>(x, xp);
    prepass_w<<<dim3(WT_ELEMS / 256), dim3(256), 0, stream>>>(wgt, wt);
    conv_gemm<<<dim3(512), dim3(512), 0, stream>>>(xp, wt, out);
  } else {
    naive_conv<<<dim3(out_size / 256), dim3(256), 0, stream>>>(x, wgt, out);
  }
}